// Round 1
// baseline (574.415 us; speedup 1.0000x reference)
//
#include <hip/hip_runtime.h>
#include <math.h>

#define B_ 64
#define T_ 2048
#define DL 1024
#define DE 512
#define DA 128
#define NF 32
#define KW 31
#define PADW 15
#define TT 128

typedef short bf16x8 __attribute__((ext_vector_type(8)));
typedef float f32x4 __attribute__((ext_vector_type(4)));

// split fp32 into bf16 hi + bf16 lo (RNE), x ~= hi + lo to ~2^-17 rel
__device__ __forceinline__ void split_bf16(float x, unsigned short &hi, unsigned short &lo) {
    unsigned u = __float_as_uint(x);
    unsigned short h = (unsigned short)((u + 0x7FFFu + ((u >> 16) & 1u)) >> 16);
    float hf = __uint_as_float((unsigned)h << 16);
    float l = x - hf;
    unsigned ul = __float_as_uint(l);
    hi = h;
    lo = (unsigned short)((ul + 0x7FFFu + ((ul >> 16) & 1u)) >> 16);
}

__device__ __forceinline__ void split8(const float4 &v0, const float4 &v1, bf16x8 &hi, bf16x8 &lo) {
    unsigned short h, l;
    split_bf16(v0.x, h, l); hi[0] = (short)h; lo[0] = (short)l;
    split_bf16(v0.y, h, l); hi[1] = (short)h; lo[1] = (short)l;
    split_bf16(v0.z, h, l); hi[2] = (short)h; lo[2] = (short)l;
    split_bf16(v0.w, h, l); hi[3] = (short)h; lo[3] = (short)l;
    split_bf16(v1.x, h, l); hi[4] = (short)h; lo[4] = (short)l;
    split_bf16(v1.y, h, l); hi[5] = (short)h; lo[5] = (short)l;
    split_bf16(v1.z, h, l); hi[6] = (short)h; lo[6] = (short)l;
    split_bf16(v1.w, h, l); hi[7] = (short)h; lo[7] = (short)l;
}

__device__ __forceinline__ float fast_tanh(float x) {
    x = fminf(fmaxf(x, -15.f), 15.f);
    float e2 = __expf(2.f * x);
    return (e2 - 1.f) * __builtin_amdgcn_rcpf(e2 + 1.f);
}

// async 16B global -> LDS (linear dest: wave-uniform base + lane*16)
__device__ __forceinline__ void gload_lds16(const float* g, float* l) {
    __builtin_amdgcn_global_load_lds((const __attribute__((address_space(1))) void*)g,
                                     (__attribute__((address_space(3))) void*)l, 16, 0, 0);
}

// ---------------- prep: split Wm [128][512] and Wloc [128][32] into bf16 hi/lo ----------------
__global__ __launch_bounds__(256) void prep_kernel(const float* __restrict__ Wm,
                                                   const float* __restrict__ Wloc,
                                                   unsigned short* __restrict__ bg_hi,
                                                   unsigned short* __restrict__ bg_lo,
                                                   unsigned short* __restrict__ bw_hi,
                                                   unsigned short* __restrict__ bw_lo) {
    int i = blockIdx.x * 256 + threadIdx.x;  // 65536 + 4096 elements
    unsigned short h, l;
    if (i < DA * DE) {
        split_bf16(Wm[i], h, l);
        bg_hi[i] = h;
        bg_lo[i] = l;
    } else {
        int j = i - DA * DE;
        split_bf16(Wloc[j], h, l);
        bw_hi[j] = h;
        bw_lo[j] = l;
    }
}

// ---------------- q = query @ Wq.T + bq  ([B,128]) ----------------
__global__ __launch_bounds__(128) void q_kernel(const float* __restrict__ query,
                                                const float* __restrict__ Wq,
                                                const float* __restrict__ bq,
                                                float* __restrict__ qbuf) {
    int b = blockIdx.x;
    int a = threadIdx.x;
    __shared__ __align__(16) float qs[DL];
    for (int i = threadIdx.x; i < DL; i += 128) qs[i] = query[(size_t)b * DL + i];
    __syncthreads();
    const float* wrow = Wq + (size_t)a * DL;
    float acc = 0.f;
#pragma unroll 8
    for (int i = 0; i < DL; i += 4) {
        float4 w = *(const float4*)(wrow + i);
        float4 q4 = *(const float4*)(qs + i);
        acc += w.x * q4.x + w.y * q4.y + w.z * q4.z + w.w * q4.w;
    }
    qbuf[(size_t)b * DA + a] = acc + bq[a];
}

// ---------------- energies via split-bf16 MFMA, pipelined ----------------
// A tile (memory fp32) staged to LDS via global_load_lds, double-buffered,
// XOR-swizzled (slot ^= t&7, pre-swizzled global source, linear LDS dest).
// B fragments (pre-split Wm/Wloc bf16) load global->reg (L2-hot, 256 KB).
// Per chunk: [B-frag loads][vmcnt(4)+s_barrier][stage next][ds_read+convert+48 MFMA].
// vmcnt never drains to 0 in the loop.
__global__ __launch_bounds__(256, 3) void energy_kernel(
    const float* __restrict__ mem,            // [B,T,512]
    const float* __restrict__ attw,           // [B,2,T]
    const unsigned short* __restrict__ bg_hi, // Wm hi bf16 [128][512]
    const unsigned short* __restrict__ bg_lo, // Wm lo bf16 [128][512]
    const unsigned short* __restrict__ bw_hi, // Wloc hi bf16 [128][32]
    const unsigned short* __restrict__ bw_lo, // Wloc lo bf16 [128][32]
    const float* __restrict__ bm,
    const float* __restrict__ Wconv,          // [32,2,31]
    const float* __restrict__ Wv,
    const float* __restrict__ bv,
    const float* __restrict__ qbuf,           // [B,128]
    float* __restrict__ e_out)                // [B,T]
{
    __shared__ __align__(16) float Ast[2][TT * NF];  // 2 x 16 KB fp32, swizzled rows of 128 B
    __shared__ __align__(16) float attw_s[2 * 160];
    __shared__ __align__(16) float wconv_s[NF * 64];
    __shared__ float qb_s[DA], wv_s[DA];
    __shared__ float e_part[2][TT];

    const int tid = threadIdx.x;
    const int b = blockIdx.y;
    const int t0 = blockIdx.x * TT;
    const int lane = tid & 63;
    const int wave = tid >> 6;
    const int wm = wave & 1, wn = wave >> 1;
    const int m = lane & 15;
    const int g = lane >> 4;   // 0..3
    const int q8 = g * 8;      // k offset of fragment (8 floats)
    const int s0 = g * 2;      // logical 16B slot of fragment start

    if (tid < DA) {
        qb_s[tid] = qbuf[(size_t)b * DA + tid] + bm[tid];
        wv_s[tid] = Wv[tid];
    }

    // stage attw slice + wconv
    for (int i = tid; i < 2 * (TT + KW - 1); i += 256) {
        int c = i / 158, j = i % 158;
        int t = t0 - PADW + j;
        attw_s[c * 160 + j] = (t >= 0 && t < T_) ? attw[((size_t)b * 2 + c) * T_ + t] : 0.f;
    }
    for (int i = tid; i < NF * 2 * KW; i += 256) {
        int f = i / 62, r = i % 62;
        wconv_s[f * 64 + r] = Wconv[i];
    }
    __syncthreads();

    // conv chunk values -> Ast[0] (fp32, swizzled store)
    for (int i = tid; i < TT * NF; i += 256) {
        int t = i >> 5, f = i & 31;
        const float* w0 = wconv_s + f * 64;
        const float* a0 = attw_s + t;
        const float* a1 = attw_s + 160 + t;
        float s = 0.f;
#pragma unroll
        for (int k = 0; k < KW; ++k) s += w0[k] * a0[k] + w0[31 + k] * a1[k];
        Ast[0][t * 32 + (((f >> 2) ^ (t & 7)) << 2) + (f & 3)] = s;
    }

    const size_t mem_base = ((size_t)b * T_ + t0) * DE;

    // issue stage of k-chunk 0 -> Ast[1] (async, 4 x 16B per thread)
#pragma unroll
    for (int r = 0; r < 4; ++r) {
        int idx = tid + 256 * r;
        int t = idx >> 3, sp = idx & 7;
        gload_lds16(mem + mem_base + (size_t)t * DE + ((sp ^ (t & 7)) << 2),
                    &Ast[1][idx << 2]);
    }

    // conv B fragments from pre-split Wloc (global, tiny)
    bf16x8 bh[4], bl[4];
#pragma unroll
    for (int ni = 0; ni < 4; ++ni) {
        int a = wn * 64 + ni * 16 + m;
        bh[ni] = *(const bf16x8*)(bw_hi + a * NF + q8);
        bl[ni] = *(const bf16x8*)(bw_lo + a * NF + q8);
    }

    // conv ds_writes visible to all waves; stage0 stays in flight
    asm volatile("s_waitcnt lgkmcnt(0)\n\ts_barrier" ::: "memory");

    f32x4 acc[4][4];
#pragma unroll
    for (int mi = 0; mi < 4; ++mi)
#pragma unroll
        for (int ni = 0; ni < 4; ++ni) {
            f32x4 z = {0.f, 0.f, 0.f, 0.f};
            acc[mi][ni] = z;
        }

    // read A fragments (swizzled), convert fp32->bf16 hi/lo, 48 MFMA
    auto compute = [&](const float* buf) {
        bf16x8 ah[4], al[4];
#pragma unroll
        for (int mi = 0; mi < 4; ++mi) {
            int t = wm * 64 + mi * 16 + m;
            int tx = t & 7;
            const float* rowp = buf + t * 32;
            float4 v0 = *(const float4*)(rowp + ((s0 ^ tx) << 2));
            float4 v1 = *(const float4*)(rowp + (((s0 + 1) ^ tx) << 2));
            split8(v0, v1, ah[mi], al[mi]);
        }
        __builtin_amdgcn_s_setprio(1);
#pragma unroll
        for (int ni = 0; ni < 4; ++ni)
#pragma unroll
            for (int mi = 0; mi < 4; ++mi) {
                acc[mi][ni] = __builtin_amdgcn_mfma_f32_16x16x32_bf16(ah[mi], bh[ni], acc[mi][ni], 0, 0, 0);
                acc[mi][ni] = __builtin_amdgcn_mfma_f32_16x16x32_bf16(ah[mi], bl[ni], acc[mi][ni], 0, 0, 0);
                acc[mi][ni] = __builtin_amdgcn_mfma_f32_16x16x32_bf16(al[mi], bh[ni], acc[mi][ni], 0, 0, 0);
            }
        __builtin_amdgcn_s_setprio(0);
    };

    compute(&Ast[0][0]);  // conv/location chunk

#pragma unroll 1
    for (int c = 0; c < 16; ++c) {
        const int k0 = c * 32;
        // (a) B fragments for chunk c: global->reg, L2-hot
#pragma unroll
        for (int ni = 0; ni < 4; ++ni) {
            int a = wn * 64 + ni * 16 + m;
            bh[ni] = *(const bf16x8*)(bg_hi + (size_t)a * DE + k0 + q8);
            bl[ni] = *(const bf16x8*)(bg_lo + (size_t)a * DE + k0 + q8);
        }
        // (b) wait chunk c's 4 stage loads (oldest); B loads + next stage stay in flight
        asm volatile("s_waitcnt vmcnt(4)\n\ts_barrier" ::: "memory");
        // (c) stage chunk c+1 -> Ast[c&1] (unconditional: keeps waitcnt counting exact;
        //     c==15 harmlessly re-stages chunk 0 into the dead buffer)
        {
            const int k0n = ((c + 1) & 15) * 32;
            const float* gk = mem + mem_base + k0n;
            float* lb = &Ast[c & 1][0];
#pragma unroll
            for (int r = 0; r < 4; ++r) {
                int idx = tid + 256 * r;
                int t = idx >> 3, sp = idx & 7;
                gload_lds16(gk + (size_t)t * DE + ((sp ^ (t & 7)) << 2), lb + (idx << 2));
            }
        }
        // (d) compute chunk c from the buffer staged last iteration
        compute(&Ast[(c + 1) & 1][0]);
    }

    // epilogue: e[t] = bv + sum_a wv[a]*tanh(acc + qb[a])
    __syncthreads();
    float wvr[4], qbr[4];
#pragma unroll
    for (int ni = 0; ni < 4; ++ni) {
        int a = wn * 64 + ni * 16 + m;
        wvr[ni] = wv_s[a];
        qbr[ni] = qb_s[a];
    }
    float bvv = bv[0];
#pragma unroll
    for (int mi = 0; mi < 4; ++mi) {
#pragma unroll
        for (int reg = 0; reg < 4; ++reg) {
            float s = 0.f;
#pragma unroll
            for (int ni = 0; ni < 4; ++ni)
                s += wvr[ni] * fast_tanh(acc[mi][ni][reg] + qbr[ni]);
            s += __shfl_xor(s, 1, 64);
            s += __shfl_xor(s, 2, 64);
            s += __shfl_xor(s, 4, 64);
            s += __shfl_xor(s, 8, 64);
            if (m == 0)
                e_part[wn][wm * 64 + mi * 16 + (lane >> 4) * 4 + reg] = s;
        }
    }
    __syncthreads();
    if (tid < TT)
        e_out[(size_t)b * T_ + t0 + tid] = e_part[0][tid] + e_part[1][tid] + bvv;
}

// ---------------- softmax over T per b ----------------
__global__ __launch_bounds__(256) void softmax_kernel(const float* __restrict__ e,
                                                      float* __restrict__ wout) {
    int b = blockIdx.x;
    int tid = threadIdx.x;
    __shared__ float red[4];
    float v[8];
    float m = -1e30f;
#pragma unroll
    for (int r = 0; r < 8; ++r) {
        v[r] = e[(size_t)b * T_ + r * 256 + tid];
        m = fmaxf(m, v[r]);
    }
#pragma unroll
    for (int off = 1; off < 64; off <<= 1) m = fmaxf(m, __shfl_xor(m, off, 64));
    if ((tid & 63) == 0) red[tid >> 6] = m;
    __syncthreads();
    m = fmaxf(fmaxf(red[0], red[1]), fmaxf(red[2], red[3]));
    __syncthreads();
    float s = 0.f;
#pragma unroll
    for (int r = 0; r < 8; ++r) {
        v[r] = expf(v[r] - m);
        s += v[r];
    }
#pragma unroll
    for (int off = 1; off < 64; off <<= 1) s += __shfl_xor(s, off, 64);
    if ((tid & 63) == 0) red[tid >> 6] = s;
    __syncthreads();
    s = red[0] + red[1] + red[2] + red[3];
    float inv = 1.0f / s;
#pragma unroll
    for (int r = 0; r < 8; ++r) wout[(size_t)b * T_ + r * 256 + tid] = v[r] * inv;
}

// ---------------- context partials (float4) ----------------
__global__ __launch_bounds__(256) void ctx_partial_kernel(const float* __restrict__ mem,
                                                          const float* __restrict__ w,
                                                          float* __restrict__ partial) {
    int b = blockIdx.y, tc = blockIdx.x;  // 16 chunks of 128 t
    int tid = threadIdx.x;
    __shared__ float ws_s[128];
    __shared__ float red[512];
    if (tid < 128) ws_s[tid] = w[(size_t)b * T_ + tc * 128 + tid];
    __syncthreads();
    int d = (tid & 127) * 4;
    int th = tid >> 7;  // two t-halves of 64
    const float* mp = mem + ((size_t)b * T_ + tc * 128 + th * 64) * DE + d;
    float a0 = 0.f, a1 = 0.f, a2 = 0.f, a3 = 0.f;
#pragma unroll 8
    for (int t = 0; t < 64; ++t) {
        float4 v = *(const float4*)(mp + (size_t)t * DE);
        float wv = ws_s[th * 64 + t];
        a0 += wv * v.x; a1 += wv * v.y; a2 += wv * v.z; a3 += wv * v.w;
    }
    if (th == 1) {
        float* r = red + (tid & 127) * 4;
        r[0] = a0; r[1] = a1; r[2] = a2; r[3] = a3;
    }
    __syncthreads();
    if (th == 0) {
        const float* r = red + tid * 4;
        float* pp = partial + ((size_t)b * 16 + tc) * DE + d;
        pp[0] = a0 + r[0]; pp[1] = a1 + r[1]; pp[2] = a2 + r[2]; pp[3] = a3 + r[3];
    }
}

// ---------------- reduce partials -> context ----------------
__global__ __launch_bounds__(512) void ctx_reduce_kernel(const float* __restrict__ partial,
                                                         float* __restrict__ ctx) {
    int b = blockIdx.x;
    int d = threadIdx.x;
    float s = 0.f;
#pragma unroll
    for (int j = 0; j < 16; ++j) s += partial[((size_t)b * 16 + j) * DE + d];
    ctx[(size_t)b * DE + d] = s;
}

extern "C" void kernel_launch(void* const* d_in, const int* in_sizes, int n_in,
                              void* d_out, int out_size, void* d_ws, size_t ws_size,
                              hipStream_t stream) {
    const float* query  = (const float*)d_in[0];
    const float* memory = (const float*)d_in[1];
    const float* attw   = (const float*)d_in[2];
    const float* Wq     = (const float*)d_in[3];
    const float* bq     = (const float*)d_in[4];
    const float* Wm     = (const float*)d_in[5];
    const float* bm     = (const float*)d_in[6];
    const float* Wconv  = (const float*)d_in[7];
    const float* Wloc   = (const float*)d_in[8];
    const float* Wv     = (const float*)d_in[9];
    const float* bv     = (const float*)d_in[10];

    float* out = (float*)d_out;
    float* ctx_out = out;          // [64,512]
    float* w_out = out + B_ * DE;  // [64,2048]

    float* ws = (float*)d_ws;
    float* qbuf = ws;                         // 8192 f
    float* ebuf = qbuf + B_ * DA;             // 131072 f
    float* partial = ebuf + (size_t)B_ * T_;  // 524288 f
    unsigned short* bg_hi = (unsigned short*)(partial + (size_t)B_ * 16 * DE);
    unsigned short* bg_lo = bg_hi + DA * DE;
    unsigned short* bw_hi = bg_lo + DA * DE;
    unsigned short* bw_lo = bw_hi + DA * NF;

    prep_kernel<<<dim3((DA * DE + DA * NF) / 256), dim3(256), 0, stream>>>(
        Wm, Wloc, bg_hi, bg_lo, bw_hi, bw_lo);
    q_kernel<<<dim3(B_), dim3(128), 0, stream>>>(query, Wq, bq, qbuf);
    energy_kernel<<<dim3(T_ / TT, B_), dim3(256), 0, stream>>>(
        memory, attw, bg_hi, bg_lo, bw_hi, bw_lo, bm, Wconv, Wv, bv, qbuf, ebuf);
    softmax_kernel<<<dim3(B_), dim3(256), 0, stream>>>(ebuf, w_out);
    ctx_partial_kernel<<<dim3(16, B_), dim3(256), 0, stream>>>(memory, w_out, partial);
    ctx_reduce_kernel<<<dim3(B_), dim3(512), 0, stream>>>(partial, ctx_out);
}

// Round 4
// 548.706 us; speedup vs baseline: 1.0469x; 1.0469x over previous
//
#include <hip/hip_runtime.h>
#include <math.h>

#define B_ 64
#define T_ 2048
#define DL 1024
#define DE 512
#define DA 128
#define NF 32
#define KW 31
#define PADW 15
#define TT 128
#define LDA 40   // bf16 LDS row stride for conv tile: 32 cols + 8 pad

typedef short bf16x8 __attribute__((ext_vector_type(8)));
typedef float f32x4 __attribute__((ext_vector_type(4)));

// split fp32 into bf16 hi + bf16 lo (RNE), x ~= hi + lo to ~2^-17 rel
__device__ __forceinline__ void split_bf16(float x, unsigned short &hi, unsigned short &lo) {
    unsigned u = __float_as_uint(x);
    unsigned short h = (unsigned short)((u + 0x7FFFu + ((u >> 16) & 1u)) >> 16);
    float hf = __uint_as_float((unsigned)h << 16);
    float l = x - hf;
    unsigned ul = __float_as_uint(l);
    hi = h;
    lo = (unsigned short)((ul + 0x7FFFu + ((ul >> 16) & 1u)) >> 16);
}

__device__ __forceinline__ void split8(const float4 &v0, const float4 &v1, bf16x8 &hi, bf16x8 &lo) {
    unsigned short h, l;
    split_bf16(v0.x, h, l); hi[0] = (short)h; lo[0] = (short)l;
    split_bf16(v0.y, h, l); hi[1] = (short)h; lo[1] = (short)l;
    split_bf16(v0.z, h, l); hi[2] = (short)h; lo[2] = (short)l;
    split_bf16(v0.w, h, l); hi[3] = (short)h; lo[3] = (short)l;
    split_bf16(v1.x, h, l); hi[4] = (short)h; lo[4] = (short)l;
    split_bf16(v1.y, h, l); hi[5] = (short)h; lo[5] = (short)l;
    split_bf16(v1.z, h, l); hi[6] = (short)h; lo[6] = (short)l;
    split_bf16(v1.w, h, l); hi[7] = (short)h; lo[7] = (short)l;
}

__device__ __forceinline__ float fast_tanh(float x) {
    x = fminf(fmaxf(x, -15.f), 15.f);
    float e2 = __expf(2.f * x);
    return (e2 - 1.f) * __builtin_amdgcn_rcpf(e2 + 1.f);
}

// ---------------- prep: split Wm [128][512] and Wloc [128][32] into bf16 hi/lo ----------------
__global__ __launch_bounds__(256) void prep_kernel(const float* __restrict__ Wm,
                                                   const float* __restrict__ Wloc,
                                                   unsigned short* __restrict__ bg_hi,
                                                   unsigned short* __restrict__ bg_lo,
                                                   unsigned short* __restrict__ bw_hi,
                                                   unsigned short* __restrict__ bw_lo) {
    int i = blockIdx.x * 256 + threadIdx.x;  // 65536 + 4096 elements
    unsigned short h, l;
    if (i < DA * DE) {
        split_bf16(Wm[i], h, l);
        bg_hi[i] = h;
        bg_lo[i] = l;
    } else {
        int j = i - DA * DE;
        split_bf16(Wloc[j], h, l);
        bw_hi[j] = h;
        bw_lo[j] = l;
    }
}

// ---------------- q = query @ Wq.T + bq  ([B,128]) ----------------
__global__ __launch_bounds__(128) void q_kernel(const float* __restrict__ query,
                                                const float* __restrict__ Wq,
                                                const float* __restrict__ bq,
                                                float* __restrict__ qbuf) {
    int b = blockIdx.x;
    int a = threadIdx.x;
    __shared__ __align__(16) float qs[DL];
    for (int i = threadIdx.x; i < DL; i += 128) qs[i] = query[(size_t)b * DL + i];
    __syncthreads();
    const float* wrow = Wq + (size_t)a * DL;
    float acc = 0.f;
#pragma unroll 8
    for (int i = 0; i < DL; i += 4) {
        float4 w = *(const float4*)(wrow + i);
        float4 q4 = *(const float4*)(qs + i);
        acc += w.x * q4.x + w.y * q4.y + w.z * q4.z + w.w * q4.w;
    }
    qbuf[(size_t)b * DA + a] = acc + bq[a];
}

// ---------------- energies via split-bf16 MFMA, barrier-free K-loop ----------------
// Each wave owns a 64t x 64a output tile; A (memory fp32) and B (pre-split Wm bf16)
// are loaded global->register, double-buffered in NAMED registers (no runtime reg
// indexing), with NO __syncthreads in the K loop. The compiler emits counted vmcnt
// for the register loads; latency hides under split-VALU + MFMA of the previous
// chunk + TLP. Conv chunk stays in LDS (pre-loop barriers only).
__global__ __launch_bounds__(256, 2) void energy_kernel(
    const float* __restrict__ mem,            // [B,T,512]
    const float* __restrict__ attw,           // [B,2,T]
    const unsigned short* __restrict__ bg_hi, // Wm hi bf16 [128][512]
    const unsigned short* __restrict__ bg_lo, // Wm lo bf16 [128][512]
    const unsigned short* __restrict__ bw_hi, // Wloc hi bf16 [128][32]
    const unsigned short* __restrict__ bw_lo, // Wloc lo bf16 [128][32]
    const float* __restrict__ bm,
    const float* __restrict__ Wconv,          // [32,2,31]
    const float* __restrict__ Wv,
    const float* __restrict__ bv,
    const float* __restrict__ qbuf,           // [B,128]
    float* __restrict__ e_out)                // [B,T]
{
    __shared__ __align__(16) unsigned short Ahi[TT * LDA];
    __shared__ __align__(16) unsigned short Alo[TT * LDA];
    __shared__ __align__(16) float attw_s[2 * 160];
    __shared__ __align__(16) float wconv_s[NF * 64];
    __shared__ float qb_s[DA], wv_s[DA];
    __shared__ float e_part[2][TT];

    const int tid = threadIdx.x;
    const int b = blockIdx.y;
    const int t0 = blockIdx.x * TT;
    const int lane = tid & 63;
    const int wave = tid >> 6;
    const int wm = wave & 1, wn = wave >> 1;
    const int m = lane & 15;
    const int g = lane >> 4;   // 0..3
    const int q8 = g * 8;      // k offset of fragment (8 elements)

    if (tid < DA) {
        qb_s[tid] = qbuf[(size_t)b * DA + tid] + bm[tid];
        wv_s[tid] = Wv[tid];
    }

    // stage attw slice + wconv
    for (int i = tid; i < 2 * (TT + KW - 1); i += 256) {
        int c = i / 158, j = i % 158;
        int t = t0 - PADW + j;
        attw_s[c * 160 + j] = (t >= 0 && t < T_) ? attw[((size_t)b * 2 + c) * T_ + t] : 0.f;
    }
    for (int i = tid; i < NF * 2 * KW; i += 256) {
        int f = i / 62, r = i % 62;
        wconv_s[f * 64 + r] = Wconv[i];
    }
    __syncthreads();

    // conv chunk: split into LDS (padded rows)
    for (int i = tid; i < TT * NF; i += 256) {
        int t = i >> 5, f = i & 31;
        const float* w0 = wconv_s + f * 64;
        const float* a0 = attw_s + t;
        const float* a1 = attw_s + 160 + t;
        float s = 0.f;
#pragma unroll
        for (int k = 0; k < KW; ++k) s += w0[k] * a0[k] + w0[31 + k] * a1[k];
        unsigned short h, l;
        split_bf16(s, h, l);
        Ahi[t * LDA + f] = h;
        Alo[t * LDA + f] = l;
    }

    // conv B fragments from pre-split Wloc (tiny, L2-hot)
    bf16x8 cbh[4], cbl[4];
#pragma unroll
    for (int ni = 0; ni < 4; ++ni) {
        int a = wn * 64 + ni * 16 + m;
        cbh[ni] = *(const bf16x8*)(bw_hi + a * NF + q8);
        cbl[ni] = *(const bf16x8*)(bw_lo + a * NF + q8);
    }
    __syncthreads();

    // per-lane base pointers for the main GEMM
    const size_t mem_base = ((size_t)b * T_ + t0) * DE;
    const float* ap = mem + mem_base + (size_t)(wm * 64 + m) * DE + q8;
    const unsigned short* bhp = bg_hi + (size_t)(wn * 64 + m) * DE + q8;
    const unsigned short* blp = bg_lo + (size_t)(wn * 64 + m) * DE + q8;

    // issue chunk 0 loads into buffer A (stay in flight across the conv MFMA)
    float4 aA[4][2];
    float4 aB[4][2];
    bf16x8 bhA[4], blA[4], bhB[4], blB[4];
#pragma unroll
    for (int mi = 0; mi < 4; ++mi) {
        const float* p = ap + (size_t)mi * 16 * DE;
        aA[mi][0] = *(const float4*)(p);
        aA[mi][1] = *(const float4*)(p + 4);
    }
#pragma unroll
    for (int ni = 0; ni < 4; ++ni) {
        const unsigned short* ph = bhp + (size_t)ni * 16 * DE;
        const unsigned short* pl = blp + (size_t)ni * 16 * DE;
        bhA[ni] = *(const bf16x8*)(ph);
        blA[ni] = *(const bf16x8*)(pl);
    }

    f32x4 acc[4][4];
#pragma unroll
    for (int mi = 0; mi < 4; ++mi)
#pragma unroll
        for (int ni = 0; ni < 4; ++ni) {
            f32x4 z = {0.f, 0.f, 0.f, 0.f};
            acc[mi][ni] = z;
        }

    // conv/location MFMA chunk (A from LDS, B from regs)
    {
        bf16x8 ah[4], al[4];
#pragma unroll
        for (int mi = 0; mi < 4; ++mi) {
            int r = (wm * 64 + mi * 16 + m) * LDA + q8;
            ah[mi] = *(const bf16x8*)(Ahi + r);
            al[mi] = *(const bf16x8*)(Alo + r);
        }
        __builtin_amdgcn_s_setprio(1);
#pragma unroll
        for (int ni = 0; ni < 4; ++ni)
#pragma unroll
            for (int mi = 0; mi < 4; ++mi) {
                acc[mi][ni] = __builtin_amdgcn_mfma_f32_16x16x32_bf16(ah[mi], cbh[ni], acc[mi][ni], 0, 0, 0);
                acc[mi][ni] = __builtin_amdgcn_mfma_f32_16x16x32_bf16(ah[mi], cbl[ni], acc[mi][ni], 0, 0, 0);
                acc[mi][ni] = __builtin_amdgcn_mfma_f32_16x16x32_bf16(al[mi], cbh[ni], acc[mi][ni], 0, 0, 0);
            }
        __builtin_amdgcn_s_setprio(0);
    }

    // main K loop: 8 iterations x 2 chunks, named double buffers, no barriers
#pragma unroll 1
    for (int it = 0; it < 8; ++it) {
        const int c = it * 2;
        // ---- even chunk c: consume buffer A, prefetch c+1 into buffer B ----
        {
            bf16x8 ah[4], al[4];
#pragma unroll
            for (int mi = 0; mi < 4; ++mi) split8(aA[mi][0], aA[mi][1], ah[mi], al[mi]);
            const float* apn = ap + (c + 1) * 32;
            const unsigned short* bhn = bhp + (c + 1) * 32;
            const unsigned short* bln = blp + (c + 1) * 32;
#pragma unroll
            for (int mi = 0; mi < 4; ++mi) {
                const float* p = apn + (size_t)mi * 16 * DE;
                aB[mi][0] = *(const float4*)(p);
                aB[mi][1] = *(const float4*)(p + 4);
            }
#pragma unroll
            for (int ni = 0; ni < 4; ++ni) {
                bhB[ni] = *(const bf16x8*)(bhn + (size_t)ni * 16 * DE);
                blB[ni] = *(const bf16x8*)(bln + (size_t)ni * 16 * DE);
            }
            __builtin_amdgcn_s_setprio(1);
#pragma unroll
            for (int ni = 0; ni < 4; ++ni)
#pragma unroll
                for (int mi = 0; mi < 4; ++mi) {
                    acc[mi][ni] = __builtin_amdgcn_mfma_f32_16x16x32_bf16(ah[mi], bhA[ni], acc[mi][ni], 0, 0, 0);
                    acc[mi][ni] = __builtin_amdgcn_mfma_f32_16x16x32_bf16(ah[mi], blA[ni], acc[mi][ni], 0, 0, 0);
                    acc[mi][ni] = __builtin_amdgcn_mfma_f32_16x16x32_bf16(al[mi], bhA[ni], acc[mi][ni], 0, 0, 0);
                }
            __builtin_amdgcn_s_setprio(0);
        }
        // ---- odd chunk c+1: consume buffer B, prefetch c+2 into buffer A ----
        {
            bf16x8 ah[4], al[4];
#pragma unroll
            for (int mi = 0; mi < 4; ++mi) split8(aB[mi][0], aB[mi][1], ah[mi], al[mi]);
            if (it < 7) {
                const float* apn = ap + (c + 2) * 32;
                const unsigned short* bhn = bhp + (c + 2) * 32;
                const unsigned short* bln = blp + (c + 2) * 32;
#pragma unroll
                for (int mi = 0; mi < 4; ++mi) {
                    const float* p = apn + (size_t)mi * 16 * DE;
                    aA[mi][0] = *(const float4*)(p);
                    aA[mi][1] = *(const float4*)(p + 4);
                }
#pragma unroll
                for (int ni = 0; ni < 4; ++ni) {
                    bhA[ni] = *(const bf16x8*)(bhn + (size_t)ni * 16 * DE);
                    blA[ni] = *(const bf16x8*)(bln + (size_t)ni * 16 * DE);
                }
            }
            __builtin_amdgcn_s_setprio(1);
#pragma unroll
            for (int ni = 0; ni < 4; ++ni)
#pragma unroll
                for (int mi = 0; mi < 4; ++mi) {
                    acc[mi][ni] = __builtin_amdgcn_mfma_f32_16x16x32_bf16(ah[mi], bhB[ni], acc[mi][ni], 0, 0, 0);
                    acc[mi][ni] = __builtin_amdgcn_mfma_f32_16x16x32_bf16(ah[mi], blB[ni], acc[mi][ni], 0, 0, 0);
                    acc[mi][ni] = __builtin_amdgcn_mfma_f32_16x16x32_bf16(al[mi], bhB[ni], acc[mi][ni], 0, 0, 0);
                }
            __builtin_amdgcn_s_setprio(0);
        }
    }

    // epilogue: e[t] = bv + sum_a wv[a]*tanh(acc + qb[a])
    float wvr[4], qbr[4];
#pragma unroll
    for (int ni = 0; ni < 4; ++ni) {
        int a = wn * 64 + ni * 16 + m;
        wvr[ni] = wv_s[a];
        qbr[ni] = qb_s[a];
    }
    float bvv = bv[0];
#pragma unroll
    for (int mi = 0; mi < 4; ++mi) {
#pragma unroll
        for (int reg = 0; reg < 4; ++reg) {
            float s = 0.f;
#pragma unroll
            for (int ni = 0; ni < 4; ++ni)
                s += wvr[ni] * fast_tanh(acc[mi][ni][reg] + qbr[ni]);
            s += __shfl_xor(s, 1, 64);
            s += __shfl_xor(s, 2, 64);
            s += __shfl_xor(s, 4, 64);
            s += __shfl_xor(s, 8, 64);
            if (m == 0)
                e_part[wn][wm * 64 + mi * 16 + (lane >> 4) * 4 + reg] = s;
        }
    }
    __syncthreads();
    if (tid < TT)
        e_out[(size_t)b * T_ + t0 + tid] = e_part[0][tid] + e_part[1][tid] + bvv;
}

// ---------------- softmax over T per b ----------------
__global__ __launch_bounds__(256) void softmax_kernel(const float* __restrict__ e,
                                                      float* __restrict__ wout) {
    int b = blockIdx.x;
    int tid = threadIdx.x;
    __shared__ float red[4];
    float v[8];
    float m = -1e30f;
#pragma unroll
    for (int r = 0; r < 8; ++r) {
        v[r] = e[(size_t)b * T_ + r * 256 + tid];
        m = fmaxf(m, v[r]);
    }
#pragma unroll
    for (int off = 1; off < 64; off <<= 1) m = fmaxf(m, __shfl_xor(m, off, 64));
    if ((tid & 63) == 0) red[tid >> 6] = m;
    __syncthreads();
    m = fmaxf(fmaxf(red[0], red[1]), fmaxf(red[2], red[3]));
    __syncthreads();
    float s = 0.f;
#pragma unroll
    for (int r = 0; r < 8; ++r) {
        v[r] = expf(v[r] - m);
        s += v[r];
    }
#pragma unroll
    for (int off = 1; off < 64; off <<= 1) s += __shfl_xor(s, off, 64);
    if ((tid & 63) == 0) red[tid >> 6] = s;
    __syncthreads();
    s = red[0] + red[1] + red[2] + red[3];
    float inv = 1.0f / s;
#pragma unroll
    for (int r = 0; r < 8; ++r) wout[(size_t)b * T_ + r * 256 + tid] = v[r] * inv;
}

// ---------------- context partials (float4) ----------------
__global__ __launch_bounds__(256) void ctx_partial_kernel(const float* __restrict__ mem,
                                                          const float* __restrict__ w,
                                                          float* __restrict__ partial) {
    int b = blockIdx.y, tc = blockIdx.x;  // 16 chunks of 128 t
    int tid = threadIdx.x;
    __shared__ float ws_s[128];
    __shared__ float red[512];
    if (tid < 128) ws_s[tid] = w[(size_t)b * T_ + tc * 128 + tid];
    __syncthreads();
    int d = (tid & 127) * 4;
    int th = tid >> 7;  // two t-halves of 64
    const float* mp = mem + ((size_t)b * T_ + tc * 128 + th * 64) * DE + d;
    float a0 = 0.f, a1 = 0.f, a2 = 0.f, a3 = 0.f;
#pragma unroll 8
    for (int t = 0; t < 64; ++t) {
        float4 v = *(const float4*)(mp + (size_t)t * DE);
        float wv = ws_s[th * 64 + t];
        a0 += wv * v.x; a1 += wv * v.y; a2 += wv * v.z; a3 += wv * v.w;
    }
    if (th == 1) {
        float* r = red + (tid & 127) * 4;
        r[0] = a0; r[1] = a1; r[2] = a2; r[3] = a3;
    }
    __syncthreads();
    if (th == 0) {
        const float* r = red + tid * 4;
        float* pp = partial + ((size_t)b * 16 + tc) * DE + d;
        pp[0] = a0 + r[0]; pp[1] = a1 + r[1]; pp[2] = a2 + r[2]; pp[3] = a3 + r[3];
    }
}

// ---------------- reduce partials -> context ----------------
__global__ __launch_bounds__(512) void ctx_reduce_kernel(const float* __restrict__ partial,
                                                         float* __restrict__ ctx) {
    int b = blockIdx.x;
    int d = threadIdx.x;
    float s = 0.f;
#pragma unroll
    for (int j = 0; j < 16; ++j) s += partial[((size_t)b * 16 + j) * DE + d];
    ctx[(size_t)b * DE + d] = s;
}

extern "C" void kernel_launch(void* const* d_in, const int* in_sizes, int n_in,
                              void* d_out, int out_size, void* d_ws, size_t ws_size,
                              hipStream_t stream) {
    const float* query  = (const float*)d_in[0];
    const float* memory = (const float*)d_in[1];
    const float* attw   = (const float*)d_in[2];
    const float* Wq     = (const float*)d_in[3];
    const float* bq     = (const float*)d_in[4];
    const float* Wm     = (const float*)d_in[5];
    const float* bm     = (const float*)d_in[6];
    const float* Wconv  = (const float*)d_in[7];
    const float* Wloc   = (const float*)d_in[8];
    const float* Wv     = (const float*)d_in[9];
    const float* bv     = (const float*)d_in[10];

    float* out = (float*)d_out;
    float* ctx_out = out;          // [64,512]
    float* w_out = out + B_ * DE;  // [64,2048]

    float* ws = (float*)d_ws;
    float* qbuf = ws;                         // 8192 f
    float* ebuf = qbuf + B_ * DA;             // 131072 f
    float* partial = ebuf + (size_t)B_ * T_;  // 524288 f
    unsigned short* bg_hi = (unsigned short*)(partial + (size_t)B_ * 16 * DE);
    unsigned short* bg_lo = bg_hi + DA * DE;
    unsigned short* bw_hi = bg_lo + DA * DE;
    unsigned short* bw_lo = bw_hi + DA * NF;

    prep_kernel<<<dim3((DA * DE + DA * NF) / 256), dim3(256), 0, stream>>>(
        Wm, Wloc, bg_hi, bg_lo, bw_hi, bw_lo);
    q_kernel<<<dim3(B_), dim3(128), 0, stream>>>(query, Wq, bq, qbuf);
    energy_kernel<<<dim3(T_ / TT, B_), dim3(256), 0, stream>>>(
        memory, attw, bg_hi, bg_lo, bw_hi, bw_lo, bm, Wconv, Wv, bv, qbuf, ebuf);
    softmax_kernel<<<dim3(B_), dim3(256), 0, stream>>>(ebuf, w_out);
    ctx_partial_kernel<<<dim3(16, B_), dim3(256), 0, stream>>>(memory, w_out, partial);
    ctx_reduce_kernel<<<dim3(B_), dim3(512), 0, stream>>>(partial, ctx_out);
}

// Round 5
// 513.397 us; speedup vs baseline: 1.1189x; 1.0688x over previous
//
#include <hip/hip_runtime.h>
#include <math.h>

#define B_ 64
#define T_ 2048
#define DL 1024
#define DE 512
#define DA 128
#define NF 32
#define KW 31
#define PADW 15
#define TT 128
#define LDA 40   // bf16 LDS row stride: 32 cols + 8 pad (2-way bank alias on b128 = free)

typedef short bf16x8 __attribute__((ext_vector_type(8)));
typedef float f32x4 __attribute__((ext_vector_type(4)));

// split fp32 into bf16 hi + bf16 lo (RNE), x ~= hi + lo to ~2^-17 rel
__device__ __forceinline__ void split_bf16(float x, unsigned short &hi, unsigned short &lo) {
    unsigned u = __float_as_uint(x);
    unsigned short h = (unsigned short)((u + 0x7FFFu + ((u >> 16) & 1u)) >> 16);
    float hf = __uint_as_float((unsigned)h << 16);
    float l = x - hf;
    unsigned ul = __float_as_uint(l);
    hi = h;
    lo = (unsigned short)((ul + 0x7FFFu + ((ul >> 16) & 1u)) >> 16);
}

__device__ __forceinline__ float fast_tanh(float x) {
    x = fminf(fmaxf(x, -15.f), 15.f);
    float e2 = __expf(2.f * x);
    return (e2 - 1.f) * __builtin_amdgcn_rcpf(e2 + 1.f);
}

// ---------------- prep: split Wm [128][512] and Wloc [128][32] into bf16 hi/lo ----------------
__global__ __launch_bounds__(256) void prep_kernel(const float* __restrict__ Wm,
                                                   const float* __restrict__ Wloc,
                                                   unsigned short* __restrict__ bg_hi,
                                                   unsigned short* __restrict__ bg_lo,
                                                   unsigned short* __restrict__ bw_hi,
                                                   unsigned short* __restrict__ bw_lo) {
    int i = blockIdx.x * 256 + threadIdx.x;  // 65536 + 4096 elements
    unsigned short h, l;
    if (i < DA * DE) {
        split_bf16(Wm[i], h, l);
        bg_hi[i] = h;
        bg_lo[i] = l;
    } else {
        int j = i - DA * DE;
        split_bf16(Wloc[j], h, l);
        bw_hi[j] = h;
        bw_lo[j] = l;
    }
}

// ---------------- q = query @ Wq.T + bq  ([B,128]) ----------------
__global__ __launch_bounds__(128) void q_kernel(const float* __restrict__ query,
                                                const float* __restrict__ Wq,
                                                const float* __restrict__ bq,
                                                float* __restrict__ qbuf) {
    int b = blockIdx.x;
    int a = threadIdx.x;
    __shared__ __align__(16) float qs[DL];
    for (int i = threadIdx.x; i < DL; i += 128) qs[i] = query[(size_t)b * DL + i];
    __syncthreads();
    const float* wrow = Wq + (size_t)a * DL;
    float acc = 0.f;
#pragma unroll 8
    for (int i = 0; i < DL; i += 4) {
        float4 w = *(const float4*)(wrow + i);
        float4 q4 = *(const float4*)(qs + i);
        acc += w.x * q4.x + w.y * q4.y + w.z * q4.z + w.w * q4.w;
    }
    qbuf[(size_t)b * DA + a] = acc + bq[a];
}

// ---------------- energies via split-bf16 MFMA ----------------
// Round-0 LDS structure + two fixes:
//  (1) MFMA pass reorder: hh x16, hl x16, lh x16 -> dependency distance 16
//      (was 3 back-to-back MFMAs on the SAME acc -> ~20cyc stall each; MfmaUtil
//       showed 3.3x MFMA-cycle inflation). Per-acc order preserved -> identical
//      numerics.
//  (2) T14 issue-early/write-late: A-tile loads for chunk c+1 are issued before
//      mfma_step(c); raw s_barrier asm (no vmcnt drain) keeps them in flight.
__global__ __launch_bounds__(256, 2) void energy_kernel(
    const float* __restrict__ mem,            // [B,T,512]
    const float* __restrict__ attw,           // [B,2,T]
    const unsigned short* __restrict__ bg_hi, // Wm hi bf16 [128][512]
    const unsigned short* __restrict__ bg_lo, // Wm lo bf16 [128][512]
    const unsigned short* __restrict__ bw_hi, // Wloc hi bf16 [128][32]
    const unsigned short* __restrict__ bw_lo, // Wloc lo bf16 [128][32]
    const float* __restrict__ bm,
    const float* __restrict__ Wconv,          // [32,2,31]
    const float* __restrict__ Wv,
    const float* __restrict__ bv,
    const float* __restrict__ qbuf,           // [B,128]
    float* __restrict__ e_out)                // [B,T]
{
    __shared__ __align__(16) unsigned short Ahi[TT * LDA];
    __shared__ __align__(16) unsigned short Alo[TT * LDA];
    __shared__ __align__(16) unsigned short Bhi[DA * LDA];
    __shared__ __align__(16) unsigned short Blo[DA * LDA];
    __shared__ __align__(16) float attw_s[2 * 160];
    __shared__ __align__(16) float wconv_s[NF * 64];
    __shared__ float qb_s[DA], wv_s[DA];
    __shared__ float e_part[2][TT];

    const int tid = threadIdx.x;
    const int b = blockIdx.y;
    const int t0 = blockIdx.x * TT;
    const int lane = tid & 63;
    const int wave = tid >> 6;
    const int wm = wave & 1, wn = wave >> 1;
    const int m = lane & 15;
    const int q8 = (lane >> 4) * 8;

    if (tid < DA) {
        qb_s[tid] = qbuf[(size_t)b * DA + tid] + bm[tid];
        wv_s[tid] = Wv[tid];
    }

    // stage attw slice + wconv
    for (int i = tid; i < 2 * (TT + KW - 1); i += 256) {
        int c = i / 158, j = i % 158;
        int t = t0 - PADW + j;
        attw_s[c * 160 + j] = (t >= 0 && t < T_) ? attw[((size_t)b * 2 + c) * T_ + t] : 0.f;
    }
    for (int i = tid; i < NF * 2 * KW; i += 256) {
        int f = i / 62, r = i % 62;
        wconv_s[f * 64 + r] = Wconv[i];
    }
    __syncthreads();

    // conv chunk: A <- conv[t][f] split; B <- pre-split Wloc copy (cols 0..31)
    for (int i = tid; i < TT * NF; i += 256) {
        int t = i >> 5, f = i & 31;
        const float* w0 = wconv_s + f * 64;
        const float* a0 = attw_s + t;
        const float* a1 = attw_s + 160 + t;
        float s = 0.f;
#pragma unroll
        for (int k = 0; k < KW; ++k) s += w0[k] * a0[k] + w0[31 + k] * a1[k];
        unsigned short h, l;
        split_bf16(s, h, l);
        Ahi[t * LDA + f] = h;
        Alo[t * LDA + f] = l;
    }
#pragma unroll
    for (int r = 0; r < 2; ++r) {
        int idx = tid + 256 * r;
        int a = idx >> 2, c8 = (idx & 3) * 8;
        *(uint4*)(Bhi + a * LDA + c8) = *(const uint4*)(bw_hi + a * NF + c8);
        *(uint4*)(Blo + a * LDA + c8) = *(const uint4*)(bw_lo + a * NF + c8);
    }
    __syncthreads();

    f32x4 acc[4][4];
#pragma unroll
    for (int mi = 0; mi < 4; ++mi)
#pragma unroll
        for (int ni = 0; ni < 4; ++ni) {
            f32x4 z = {0.f, 0.f, 0.f, 0.f};
            acc[mi][ni] = z;
        }

    // MFMA step: fragments up-front, 3 passes of 16 independent MFMAs.
    // Per-acc order stays hh, hl, lh (numerics identical to the per-acc triple).
    auto mfma_step = [&]() {
        bf16x8 ah[4], al[4], bh[4], bl[4];
#pragma unroll
        for (int mi = 0; mi < 4; ++mi) {
            int r = (wm * 64 + mi * 16 + m) * LDA + q8;
            ah[mi] = *(const bf16x8*)(Ahi + r);
            al[mi] = *(const bf16x8*)(Alo + r);
        }
#pragma unroll
        for (int ni = 0; ni < 4; ++ni) {
            int r = (wn * 64 + ni * 16 + m) * LDA + q8;
            bh[ni] = *(const bf16x8*)(Bhi + r);
            bl[ni] = *(const bf16x8*)(Blo + r);
        }
        __builtin_amdgcn_s_setprio(1);
#pragma unroll
        for (int ni = 0; ni < 4; ++ni)
#pragma unroll
            for (int mi = 0; mi < 4; ++mi)
                acc[mi][ni] = __builtin_amdgcn_mfma_f32_16x16x32_bf16(ah[mi], bh[ni], acc[mi][ni], 0, 0, 0);
#pragma unroll
        for (int ni = 0; ni < 4; ++ni)
#pragma unroll
            for (int mi = 0; mi < 4; ++mi)
                acc[mi][ni] = __builtin_amdgcn_mfma_f32_16x16x32_bf16(ah[mi], bl[ni], acc[mi][ni], 0, 0, 0);
#pragma unroll
        for (int ni = 0; ni < 4; ++ni)
#pragma unroll
            for (int mi = 0; mi < 4; ++mi)
                acc[mi][ni] = __builtin_amdgcn_mfma_f32_16x16x32_bf16(al[mi], bh[ni], acc[mi][ni], 0, 0, 0);
        __builtin_amdgcn_s_setprio(0);
    };

    const size_t mem_base = ((size_t)b * T_ + t0) * DE;

    // T14 prologue: issue chunk-0 A loads (in flight across conv mfma_step)
    float4 rA[4];
#pragma unroll
    for (int r = 0; r < 4; ++r) {
        int idx = tid + 256 * r;
        int t = idx >> 3, c4 = (idx & 7) * 4;
        rA[r] = *(const float4*)(mem + mem_base + (size_t)t * DE + c4);
    }

    mfma_step();  // conv/location chunk

#pragma unroll 1
    for (int c = 0; c < 16; ++c) {
        const int k0 = c * 32;
        // all waves done reading LDS of previous chunk; do NOT drain vmcnt
        asm volatile("s_barrier" ::: "memory");
        // B chunk loads (L2-hot); their latency hides under the A-split VALU
        uint4 rbh[2], rbl[2];
#pragma unroll
        for (int r = 0; r < 2; ++r) {
            int idx = tid + 256 * r;
            int a = idx >> 2, c8 = (idx & 3) * 8;
            rbh[r] = *(const uint4*)(bg_hi + (size_t)a * DE + k0 + c8);
            rbl[r] = *(const uint4*)(bg_lo + (size_t)a * DE + k0 + c8);
        }
        // A split + LDS write (rA was prefetched one chunk ago)
#pragma unroll
        for (int r = 0; r < 4; ++r) {
            int idx = tid + 256 * r;
            int t = idx >> 3, c4 = (idx & 7) * 4;
            unsigned short h0, l0, h1, l1, h2, l2, h3, l3;
            split_bf16(rA[r].x, h0, l0);
            split_bf16(rA[r].y, h1, l1);
            split_bf16(rA[r].z, h2, l2);
            split_bf16(rA[r].w, h3, l3);
            ushort4 hv = {h0, h1, h2, h3};
            ushort4 lv = {l0, l1, l2, l3};
            *(ushort4*)(Ahi + t * LDA + c4) = hv;
            *(ushort4*)(Alo + t * LDA + c4) = lv;
        }
        // B LDS write
#pragma unroll
        for (int r = 0; r < 2; ++r) {
            int idx = tid + 256 * r;
            int a = idx >> 2, c8 = (idx & 3) * 8;
            *(uint4*)(Bhi + a * LDA + c8) = rbh[r];
            *(uint4*)(Blo + a * LDA + c8) = rbl[r];
        }
        // T14: issue next chunk's A loads; they stay in flight across mfma_step
        if (c < 15) {
            const int k0n = k0 + 32;
#pragma unroll
            for (int r = 0; r < 4; ++r) {
                int idx = tid + 256 * r;
                int t = idx >> 3, c4 = (idx & 7) * 4;
                rA[r] = *(const float4*)(mem + mem_base + (size_t)t * DE + k0n + c4);
            }
        }
        // ds_writes visible to all waves; vmcnt (A prefetch) NOT drained
        asm volatile("s_waitcnt lgkmcnt(0)\n\ts_barrier" ::: "memory");
        mfma_step();
    }

    // epilogue: e[t] = bv + sum_a wv[a]*tanh(acc + qb[a])
    float wvr[4], qbr[4];
#pragma unroll
    for (int ni = 0; ni < 4; ++ni) {
        int a = wn * 64 + ni * 16 + m;
        wvr[ni] = wv_s[a];
        qbr[ni] = qb_s[a];
    }
    float bvv = bv[0];
#pragma unroll
    for (int mi = 0; mi < 4; ++mi) {
#pragma unroll
        for (int reg = 0; reg < 4; ++reg) {
            float s = 0.f;
#pragma unroll
            for (int ni = 0; ni < 4; ++ni)
                s += wvr[ni] * fast_tanh(acc[mi][ni][reg] + qbr[ni]);
            s += __shfl_xor(s, 1, 64);
            s += __shfl_xor(s, 2, 64);
            s += __shfl_xor(s, 4, 64);
            s += __shfl_xor(s, 8, 64);
            if (m == 0)
                e_part[wn][wm * 64 + mi * 16 + (lane >> 4) * 4 + reg] = s;
        }
    }
    __syncthreads();
    if (tid < TT)
        e_out[(size_t)b * T_ + t0 + tid] = e_part[0][tid] + e_part[1][tid] + bvv;
}

// ---------------- softmax over T per b ----------------
__global__ __launch_bounds__(256) void softmax_kernel(const float* __restrict__ e,
                                                      float* __restrict__ wout) {
    int b = blockIdx.x;
    int tid = threadIdx.x;
    __shared__ float red[4];
    float v[8];
    float m = -1e30f;
#pragma unroll
    for (int r = 0; r < 8; ++r) {
        v[r] = e[(size_t)b * T_ + r * 256 + tid];
        m = fmaxf(m, v[r]);
    }
#pragma unroll
    for (int off = 1; off < 64; off <<= 1) m = fmaxf(m, __shfl_xor(m, off, 64));
    if ((tid & 63) == 0) red[tid >> 6] = m;
    __syncthreads();
    m = fmaxf(fmaxf(red[0], red[1]), fmaxf(red[2], red[3]));
    __syncthreads();
    float s = 0.f;
#pragma unroll
    for (int r = 0; r < 8; ++r) {
        v[r] = expf(v[r] - m);
        s += v[r];
    }
#pragma unroll
    for (int off = 1; off < 64; off <<= 1) s += __shfl_xor(s, off, 64);
    if ((tid & 63) == 0) red[tid >> 6] = s;
    __syncthreads();
    s = red[0] + red[1] + red[2] + red[3];
    float inv = 1.0f / s;
#pragma unroll
    for (int r = 0; r < 8; ++r) wout[(size_t)b * T_ + r * 256 + tid] = v[r] * inv;
}

// ---------------- context partials (float4) ----------------
__global__ __launch_bounds__(256) void ctx_partial_kernel(const float* __restrict__ mem,
                                                          const float* __restrict__ w,
                                                          float* __restrict__ partial) {
    int b = blockIdx.y, tc = blockIdx.x;  // 16 chunks of 128 t
    int tid = threadIdx.x;
    __shared__ float ws_s[128];
    __shared__ float red[512];
    if (tid < 128) ws_s[tid] = w[(size_t)b * T_ + tc * 128 + tid];
    __syncthreads();
    int d = (tid & 127) * 4;
    int th = tid >> 7;  // two t-halves of 64
    const float* mp = mem + ((size_t)b * T_ + tc * 128 + th * 64) * DE + d;
    float a0 = 0.f, a1 = 0.f, a2 = 0.f, a3 = 0.f;
#pragma unroll 8
    for (int t = 0; t < 64; ++t) {
        float4 v = *(const float4*)(mp + (size_t)t * DE);
        float wv = ws_s[th * 64 + t];
        a0 += wv * v.x; a1 += wv * v.y; a2 += wv * v.z; a3 += wv * v.w;
    }
    if (th == 1) {
        float* r = red + (tid & 127) * 4;
        r[0] = a0; r[1] = a1; r[2] = a2; r[3] = a3;
    }
    __syncthreads();
    if (th == 0) {
        const float* r = red + tid * 4;
        float* pp = partial + ((size_t)b * 16 + tc) * DE + d;
        pp[0] = a0 + r[0]; pp[1] = a1 + r[1]; pp[2] = a2 + r[2]; pp[3] = a3 + r[3];
    }
}

// ---------------- reduce partials -> context ----------------
__global__ __launch_bounds__(512) void ctx_reduce_kernel(const float* __restrict__ partial,
                                                         float* __restrict__ ctx) {
    int b = blockIdx.x;
    int d = threadIdx.x;
    float s = 0.f;
#pragma unroll
    for (int j = 0; j < 16; ++j) s += partial[((size_t)b * 16 + j) * DE + d];
    ctx[(size_t)b * DE + d] = s;
}

extern "C" void kernel_launch(void* const* d_in, const int* in_sizes, int n_in,
                              void* d_out, int out_size, void* d_ws, size_t ws_size,
                              hipStream_t stream) {
    const float* query  = (const float*)d_in[0];
    const float* memory = (const float*)d_in[1];
    const float* attw   = (const float*)d_in[2];
    const float* Wq     = (const float*)d_in[3];
    const float* bq     = (const float*)d_in[4];
    const float* Wm     = (const float*)d_in[5];
    const float* bm     = (const float*)d_in[6];
    const float* Wconv  = (const float*)d_in[7];
    const float* Wloc   = (const float*)d_in[8];
    const float* Wv     = (const float*)d_in[9];
    const float* bv     = (const float*)d_in[10];

    float* out = (float*)d_out;
    float* ctx_out = out;          // [64,512]
    float* w_out = out + B_ * DE;  // [64,2048]

    float* ws = (float*)d_ws;
    float* qbuf = ws;                         // 8192 f
    float* ebuf = qbuf + B_ * DA;             // 131072 f
    float* partial = ebuf + (size_t)B_ * T_;  // 524288 f
    unsigned short* bg_hi = (unsigned short*)(partial + (size_t)B_ * 16 * DE);
    unsigned short* bg_lo = bg_hi + DA * DE;
    unsigned short* bw_hi = bg_lo + DA * DE;
    unsigned short* bw_lo = bw_hi + DA * NF;

    prep_kernel<<<dim3((DA * DE + DA * NF) / 256), dim3(256), 0, stream>>>(
        Wm, Wloc, bg_hi, bg_lo, bw_hi, bw_lo);
    q_kernel<<<dim3(B_), dim3(128), 0, stream>>>(query, Wq, bq, qbuf);
    energy_kernel<<<dim3(T_ / TT, B_), dim3(256), 0, stream>>>(
        memory, attw, bg_hi, bg_lo, bw_hi, bw_lo, bm, Wconv, Wv, bv, qbuf, ebuf);
    softmax_kernel<<<dim3(B_), dim3(256), 0, stream>>>(ebuf, w_out);
    ctx_partial_kernel<<<dim3(16, B_), dim3(256), 0, stream>>>(memory, w_out, partial);
    ctx_reduce_kernel<<<dim3(B_), dim3(512), 0, stream>>>(partial, ctx_out);
}